// Round 5
// baseline (4964.341 us; speedup 1.0000x reference)
//
#include <hip/hip_runtime.h>
#include <hip/hip_bf16.h>

#define TT 512
#define NB 1024

typedef float f32x4 __attribute__((ext_vector_type(4)));
typedef __bf16 bf16x8 __attribute__((ext_vector_type(8)));

// ---- workspace layout (bf16 elems). All matrices stored as A-fragments for
// the TRANSPOSED GEMM  C^T[feature][batch] = W^T @ act^T :
//   frag(mt, kt, lane, j) at ((mt*KT + kt)*512 + lane*8 + j)
//   value = W[kappa][16*mt + (lane&15)]
#define OFF_HP 0
#define OFF_CP 65536
#define OFF_M  81920
#define OFF_PO 212992
#define OFF_R1 278528
#define TOT    344064

// h-history: hist[((t*64+blk)*8+fr)*512 + lane*8 + j], bf16.
#define H_OFF_BYTES (1u << 20)
#define H_ELEMS ((size_t)TT * 64 * 8 * 512)

// Force true register residency: the value's def becomes this asm, so the
// compiler cannot rematerialize it from memory inside the loop.
#define KEEP(v) asm volatile("" : "+v"(v))

__device__ __forceinline__ bf16x8 as_bf(const f32x4 v) {
  union U { f32x4 f; bf16x8 b; } u; u.f = v; return u.b;
}

__global__ __launch_bounds__(256) void pack_weights(
    const float* __restrict__ Whp, const float* __restrict__ Wm,
    const float* __restrict__ Wcp, const float* __restrict__ Whpost,
    const float* __restrict__ Wr1, __bf16* __restrict__ wsp) {
  int id = blockIdx.x * 256 + threadIdx.x;
  if (id >= TOT) return;
  int j = id & 7, lane = (id >> 3) & 63;
  int lq = lane >> 4, l15 = lane & 15;
  int rel, KT; const float* W; bool perm = true;
  if (id < OFF_CP)      { rel = id;          KT = 8;  W = Whp; }
  else if (id < OFF_M)  { rel = id - OFF_CP; KT = 2;  W = Wcp; perm = false; }
  else if (id < OFF_PO) { rel = id - OFF_M;  KT = 16; W = Wm; }
  else if (id < OFF_R1) { rel = id - OFF_PO; KT = 8;  W = Whpost; }
  else                  { rel = id - OFF_R1; KT = 8;  W = Wr1; }
  int ktm = rel >> 9;
  int kt = ktm % KT, mt = ktm / KT;
  int phi = 16 * mt + l15;
  int kk;
  if (perm) {
    int kb = (kt >= 8) ? kt - 8 : kt;          // only mesh has kt>=8
    kk = 32 * kb + 16 * (j >> 2) + 4 * lq + (j & 3);
    if (kt >= 8) kk += 256;                    // cp half of the concat
  } else {
    kk = 32 * kt + 8 * lq + j;
  }
  wsp[id] = (__bf16)W[kk * 256 + phi];
}

__device__ __forceinline__ float tanh_fast(float x) {
  float t = __expf(2.0f * x);
  return 1.0f - __fdividef(2.0f, t + 1.0f);
}

#define MFMA(a, b, c) __builtin_amdgcn_mfma_f32_16x16x32_bf16((a), (b), (c), 0, 0, 0)

// tanh + pack two mt-accumulators into ONE B-fragment (index fr).
__device__ __forceinline__ bf16x8 pack2(__bf16* region, int fr, int lane,
                                        const f32x4& a0, const f32x4& a1) {
  bf16x8 f;
  #pragma unroll
  for (int r = 0; r < 4; ++r) {
    f[r]     = (__bf16)tanh_fast(a0[r]);
    f[4 + r] = (__bf16)tanh_fast(a1[r]);
  }
  *(bf16x8*)(region + fr * 512 + lane * 8) = f;
  return f;
}

// Raw barrier: make LDS writes visible (lgkmcnt only) WITHOUT draining vmcnt.
__device__ __forceinline__ void barrier_lds() {
  asm volatile("s_waitcnt lgkmcnt(0)" ::: "memory");
  __builtin_amdgcn_s_barrier();
  asm volatile("" ::: "memory");
}

// ---------------------------------------------------------------------------
// rnn_seq_c: 4 waves x 4 m-tiles, waves_per_eu(1,1) -> 512-VGPR budget.
// ALL recurrence weights register-pinned (hp 32 + mesh 64 + cp 8 frags = 416
// VGPRs); po streamed via rolling-8 window; out-head deferred via hist.
// Per-CU LDS ops/step drop ~500 -> ~190 (B-frag reads halve with wave count,
// weight LDS reads eliminated). MFMA order per output identical to R4.
// ---------------------------------------------------------------------------
__global__ __launch_bounds__(256)
__attribute__((amdgpu_waves_per_eu(1, 1)))
void rnn_seq_c(
    const float* __restrict__ x, const __bf16* __restrict__ wsp,
    __bf16* __restrict__ hist,
    const float* __restrict__ bhp, const float* __restrict__ bcp,
    const float* __restrict__ bm, const float* __restrict__ bhpost) {
  __shared__ __align__(16) __bf16 hB[8 * 512];   // h state as B-frags (8K)
  __shared__ __align__(16) __bf16 mB[16 * 512];  // [hpB | cpB] (16K)
  __shared__ __align__(16) __bf16 uB[8 * 512];   // mesh output (8K)
  __shared__ float lb[4 * 256];                  // bhp,bcp,bm,bhpost (4K)

  const int tid  = threadIdx.x;
  const int wv   = tid >> 6;      // 0..3, owns m-tiles 4wv..4wv+3
  const int lane = tid & 63;
  const int lq   = lane >> 4, l15 = lane & 15;
  const int n0   = blockIdx.x * 16;
  const int mt0  = 4 * wv;
  const int f0   = 2 * wv;        // B-frag indices f0, f0+1 produced

  if (tid < 256) {
    lb[0 * 256 + tid] = bhp[tid];
    lb[1 * 256 + tid] = bcp[tid];
    lb[2 * 256 + tid] = bm[tid];
    lb[3 * 256 + tid] = bhpost[tid];
  }
  for (int i = tid; i < 8 * 512; i += 256) hB[i] = (__bf16)0.0f;

  #define BIAS(a, m) (*(const f32x4*)(lb + (a) * 256 + (m) * 16 + 4 * lq))

  // ---- pinned weights: hp 32 frags + mesh 64 + cp 8 = 416 VGPRs ----
  f32x4 hpw[32], wmw[64], cpw[8];
  {
    #pragma unroll
    for (int mt = 0; mt < 4; ++mt) {
      const __bf16* hp0 = wsp + OFF_HP + (size_t)((mt0 + mt) * 8) * 512 + lane * 8;
      const __bf16* mm0 = wsp + OFF_M  + (size_t)((mt0 + mt) * 16) * 512 + lane * 8;
      const __bf16* cc0 = wsp + OFF_CP + (size_t)((mt0 + mt) * 2) * 512 + lane * 8;
      #pragma unroll
      for (int kt = 0; kt < 8; ++kt)  hpw[mt * 8 + kt]  = *(const f32x4*)(hp0 + kt * 512);
      #pragma unroll
      for (int i = 0; i < 16; ++i)    wmw[mt * 16 + i]  = *(const f32x4*)(mm0 + i * 512);
      #pragma unroll
      for (int k = 0; k < 2; ++k)     cpw[mt * 2 + k]   = *(const f32x4*)(cc0 + k * 512);
    }
  }
  #pragma unroll
  for (int i = 0; i < 32; ++i) KEEP(hpw[i]);
  #pragma unroll
  for (int i = 0; i < 64; ++i) KEEP(wmw[i]);
  #pragma unroll
  for (int i = 0; i < 8; ++i)  KEEP(cpw[i]);

  const __bf16* po_p = wsp + OFF_PO + (size_t)(mt0 * 8) * 512 + lane * 8;
  __bf16* hst = hist + (size_t)(blockIdx.x * 8 + f0) * 512 + lane * 8;

  __syncthreads();

  const float* xbase = x + (size_t)(n0 + l15) * 64 + 8 * lq;
  f32x4 xr0 = *(const f32x4*)(xbase);
  f32x4 xr1 = *(const f32x4*)(xbase + 4);
  f32x4 xr2 = *(const f32x4*)(xbase + 32);
  f32x4 xr3 = *(const f32x4*)(xbase + 36);

  for (int t = 0; t < TT; ++t) {
    bf16x8 Bx0, Bx1;
    #pragma unroll
    for (int j = 0; j < 4; ++j) {
      Bx0[j] = (__bf16)xr0[j]; Bx0[4 + j] = (__bf16)xr1[j];
      Bx1[j] = (__bf16)xr2[j]; Bx1[4 + j] = (__bf16)xr3[j];
    }

    // ---- stage 1: hp = h@Whp + bhp ; cp = x@Wcp + bcp (all weights in regs)
    f32x4 ah[4];
    #pragma unroll
    for (int mt = 0; mt < 4; ++mt) ah[mt] = BIAS(0, mt0 + mt);
    #pragma unroll
    for (int kt = 0; kt < 8; ++kt) {       // kt-major: bh used 4x then dead
      bf16x8 bh = *(const bf16x8*)(hB + kt * 512 + lane * 8);
      #pragma unroll
      for (int mt = 0; mt < 4; ++mt)
        ah[mt] = MFMA(as_bf(hpw[mt * 8 + kt]), bh, ah[mt]);
    }
    f32x4 ac[4];
    #pragma unroll
    for (int mt = 0; mt < 4; ++mt) {
      ac[mt] = BIAS(1, mt0 + mt);
      ac[mt] = MFMA(as_bf(cpw[mt * 2 + 0]), Bx0, ac[mt]);
      ac[mt] = MFMA(as_bf(cpw[mt * 2 + 1]), Bx1, ac[mt]);
    }
    pack2(mB,           f0,     lane, ah[0], ah[1]);
    pack2(mB,           f0 + 1, lane, ah[2], ah[3]);
    pack2(mB + 8 * 512, f0,     lane, ac[0], ac[1]);
    pack2(mB + 8 * 512, f0 + 1, lane, ac[2], ac[3]);
    barrier_lds();  // B1

    // ---- stage 2: u = cat@Wm + bm (mesh fully in regs) ----
    // issue po window first (flies across stage 2 + B2 into stage 3);
    // consumption order c: kt = c>>2, mt = c&3, frag g = mt*8 + kt.
    bf16x8 pob[8];
    #pragma unroll
    for (int c = 0; c < 8; ++c) {
      int g = (c & 3) * 8 + (c >> 2);
      pob[c] = *(const bf16x8*)(po_p + g * 512);
    }
    {  // next step's x (in flight across B2/B3)
      int tn = (t + 1 < TT) ? t + 1 : TT - 1;
      const float* xp = xbase + (size_t)tn * NB * 64;
      xr0 = *(const f32x4*)(xp);      xr1 = *(const f32x4*)(xp + 4);
      xr2 = *(const f32x4*)(xp + 32); xr3 = *(const f32x4*)(xp + 36);
    }
    f32x4 am[4];
    #pragma unroll
    for (int mt = 0; mt < 4; ++mt) am[mt] = BIAS(2, mt0 + mt);
    #pragma unroll
    for (int i = 0; i < 16; ++i) {         // i-major: bm used 4x then dead
      bf16x8 bmv = *(const bf16x8*)(mB + i * 512 + lane * 8);
      #pragma unroll
      for (int mt = 0; mt < 4; ++mt)
        am[mt] = MFMA(as_bf(wmw[mt * 16 + i]), bmv, am[mt]);
    }
    pack2(uB, f0,     lane, am[0], am[1]);
    pack2(uB, f0 + 1, lane, am[2], am[3]);
    barrier_lds();  // B2

    // ---- stage 3: h = tanh(u @ Whpost + bhpost) ; store h to history ----
    f32x4 ap[4];
    #pragma unroll
    for (int mt = 0; mt < 4; ++mt) ap[mt] = BIAS(3, mt0 + mt);
    #pragma unroll
    for (int kt = 0; kt < 8; ++kt) {       // kt-major: bu used 4x then dead
      bf16x8 bu = *(const bf16x8*)(uB + kt * 512 + lane * 8);
      #pragma unroll
      for (int mt = 0; mt < 4; ++mt) {
        int c = kt * 4 + mt;
        ap[mt] = MFMA(pob[c & 7], bu, ap[mt]);
        if (c + 8 < 32) {                  // rolling window refill
          int g = ((c + 8) & 3) * 8 + ((c + 8) >> 2);
          pob[c & 7] = *(const bf16x8*)(po_p + g * 512);
        }
      }
    }
    bf16x8 h0 = pack2(hB, f0,     lane, ap[0], ap[1]);
    bf16x8 h1 = pack2(hB, f0 + 1, lane, ap[2], ap[3]);
    {
      __bf16* hw = hst + (size_t)t * (64 * 8 * 512);
      *(bf16x8*)(hw)       = h0;           // fire-and-forget
      *(bf16x8*)(hw + 512) = h1;
    }
    barrier_lds();  // B3
  }
  #undef BIAS
}

// ---------------------------------------------------------------------------
// head: out[t] = relu(h(t)@Wr1 + br1)@Wr2 + br2, fully parallel.
// Same frag data + same MFMA/reduction order as before -> identical output.
// ---------------------------------------------------------------------------
__global__ __launch_bounds__(512) void head_out(
    const __bf16* __restrict__ wsp, const __bf16* __restrict__ hist,
    const float* __restrict__ br1, const float* __restrict__ Wr2,
    const float* __restrict__ br2, float* __restrict__ out) {
  __shared__ float outp[128];
  const int tid  = threadIdx.x;
  const int wv   = tid >> 6;
  const int lane = tid & 63;
  const int lq   = lane >> 4;
  const int t    = blockIdx.x;
  const int nb0  = blockIdx.y * 16;
  const int mt0  = 2 * wv;

  f32x4 r1w[16];
  {
    const __bf16* r1p = wsp + OFF_R1 + (size_t)(mt0 * 8) * 512 + lane * 8;
    #pragma unroll
    for (int i = 0; i < 16; ++i) r1w[i] = *(const f32x4*)(r1p + i * 512);
  }
  #pragma unroll
  for (int i = 0; i < 16; ++i) KEEP(r1w[i]);

  const f32x4 w2a = *(const f32x4*)(Wr2 + mt0 * 16 + 4 * lq);
  const f32x4 w2b = *(const f32x4*)(Wr2 + (mt0 + 1) * 16 + 4 * lq);
  const f32x4 b0  = *(const f32x4*)(br1 + mt0 * 16 + 4 * lq);
  const f32x4 b1  = *(const f32x4*)(br1 + (mt0 + 1) * 16 + 4 * lq);
  const float br2v = br2[0];

  for (int nb = nb0; nb < nb0 + 16; ++nb) {
    const __bf16* hp = hist + (size_t)((t * 64 + nb) * 8) * 512 + lane * 8;
    bf16x8 Bh[8];
    #pragma unroll
    for (int k = 0; k < 8; ++k) Bh[k] = *(const bf16x8*)(hp + k * 512);
    f32x4 ar0 = b0, ar1 = b1;
    #pragma unroll
    for (int i = 0; i < 16; ++i) {
      if (i < 8) ar0 = MFMA(as_bf(r1w[i]), Bh[i], ar0);
      else       ar1 = MFMA(as_bf(r1w[i]), Bh[i - 8], ar1);
    }
    float p = 0.f;
    #pragma unroll
    for (int r = 0; r < 4; ++r)
      p += fmaxf(ar0[r], 0.f) * w2a[r] + fmaxf(ar1[r], 0.f) * w2b[r];
    p += __shfl_xor(p, 16, 64);
    p += __shfl_xor(p, 32, 64);
    if (lane < 16) outp[wv * 16 + lane] = p;
    __syncthreads();
    if (tid < 16) {
      float s = br2v;
      #pragma unroll
      for (int w = 0; w < 8; ++w) s += outp[w * 16 + tid];
      out[(size_t)t * NB + nb * 16 + tid] = s;
    }
    __syncthreads();
  }
}

// ---------------------------------------------------------------------------
// Fallback (small ws): R4 variant-B kernel, unchanged.
// ---------------------------------------------------------------------------
__global__ __launch_bounds__(512)
__attribute__((amdgpu_waves_per_eu(2, 2)))
void rnn_seq(
    const float* __restrict__ x, const __bf16* __restrict__ wsp,
    const float* __restrict__ bhp, const float* __restrict__ bcp,
    const float* __restrict__ bm, const float* __restrict__ bhpost,
    const float* __restrict__ br1, const float* __restrict__ Wr2,
    const float* __restrict__ br2, float* __restrict__ out) {
  __shared__ __align__(16) __bf16 hB[8 * 512];
  __shared__ __align__(16) __bf16 mB[16 * 512];
  __shared__ __align__(16) __bf16 uB[8 * 512];
  __shared__ __align__(16) __bf16 r1L[112 * 512];
  __shared__ float lb[5 * 256];
  __shared__ float outp[128];

  const int tid  = threadIdx.x;
  const int wv   = tid >> 6;
  const int lane = tid & 63;
  const int lq   = lane >> 4, l15 = lane & 15;
  const int n0   = blockIdx.x * 16;
  const int mt0  = 2 * wv;

  if (tid < 256) {
    lb[0 * 256 + tid] = bhp[tid];
    lb[1 * 256 + tid] = bcp[tid];
    lb[2 * 256 + tid] = bm[tid];
    lb[3 * 256 + tid] = bhpost[tid];
    lb[4 * 256 + tid] = br1[tid];
  }
  for (int i = tid; i < 8 * 512; i += 512) hB[i] = (__bf16)0.0f;

  for (int v = tid; v < 112 * 64; v += 512) {
    int frag = v >> 6, lp = v & 63;
    int mt = frag / 7, kt = frag - mt * 7;
    ((bf16x8*)r1L)[v] =
        *(const bf16x8*)(wsp + OFF_R1 + (size_t)(mt * 8 + kt) * 512 + lp * 8);
  }
  const float br2v = br2[0];

  #define BIAS(a, m) (*(const f32x4*)(lb + (a) * 256 + (m) * 16 + 4 * lq))
  const f32x4 w2a = *(const f32x4*)(Wr2 + mt0 * 16 + 4 * lq);
  const f32x4 w2b = *(const f32x4*)(Wr2 + (mt0 + 1) * 16 + 4 * lq);

  f32x4 wm0f[16]; bf16x8 wm1[16];
  {
    const __bf16* mp = wsp + OFF_M + (size_t)(mt0 * 16) * 512 + lane * 8;
    #pragma unroll
    for (int kt = 0; kt < 16; ++kt) {
      wm0f[kt] = *(const f32x4*)(mp + kt * 512);
      wm1[kt]  = *(const bf16x8*)(mp + (16 + kt) * 512);
    }
  }
  #pragma unroll
  for (int i = 0; i < 16; ++i) KEEP(wm0f[i]);

  const __bf16* hp_p = wsp + OFF_HP + (size_t)(mt0 * 8) * 512 + lane * 8;
  const __bf16* r1_p = wsp + OFF_R1 + (size_t)(mt0 * 8) * 512 + lane * 8;
  const __bf16* cp_p = wsp + OFF_CP + (size_t)(mt0 * 2) * 512 + lane * 8;
  const __bf16* po_p = wsp + OFF_PO + (size_t)(mt0 * 8) * 512 + lane * 8;
  const __bf16* r1Lp = r1L + (size_t)(mt0 * 7) * 512 + lane * 8;

  __syncthreads();

  const float* xbase = x + (size_t)(n0 + l15) * 64 + 8 * lq;
  f32x4 xr0 = *(const f32x4*)(xbase);
  f32x4 xr1 = *(const f32x4*)(xbase + 4);
  f32x4 xr2 = *(const f32x4*)(xbase + 32);
  f32x4 xr3 = *(const f32x4*)(xbase + 36);

  bf16x8 hpb[8];
  #pragma unroll
  for (int p = 0; p < 8; ++p) hpb[p] = *(const bf16x8*)(hp_p + p * 512);

  for (int t = 0; t < TT; ++t) {
    if (t >= 2 && tid < 16) {
      float s = br2v;
      #pragma unroll
      for (int w = 0; w < 8; ++w) s += outp[w * 16 + tid];
      out[(size_t)(t - 2) * NB + n0 + tid] = s;
    }

    bf16x8 Bx0, Bx1;
    #pragma unroll
    for (int j = 0; j < 4; ++j) {
      Bx0[j] = (__bf16)xr0[j]; Bx0[4 + j] = (__bf16)xr1[j];
      Bx1[j] = (__bf16)xr2[j]; Bx1[4 + j] = (__bf16)xr3[j];
    }

    bf16x8 cpb[4];
    #pragma unroll
    for (int p = 0; p < 4; ++p) cpb[p] = *(const bf16x8*)(cp_p + p * 512);
    bf16x8 r1k7a = *(const bf16x8*)(r1_p + 7 * 512);
    bf16x8 r1k7b = *(const bf16x8*)(r1_p + 15 * 512);
    bf16x8 Bh[8];
    #pragma unroll
    for (int kt = 0; kt < 8; ++kt)
      Bh[kt] = *(const bf16x8*)(hB + kt * 512 + lane * 8);

    f32x4 ah0 = BIAS(0, mt0), ah1 = BIAS(0, mt0 + 1);
    #pragma unroll
    for (int i = 0; i < 16; ++i) {
      bf16x8 a = hpb[i & 7];
      if (i < 8) ah0 = MFMA(a, Bh[i & 7], ah0);
      else       ah1 = MFMA(a, Bh[i & 7], ah1);
      if (i + 8 < 16) hpb[i & 7] = *(const bf16x8*)(hp_p + (i + 8) * 512);
    }
    f32x4 ac0 = BIAS(1, mt0), ac1 = BIAS(1, mt0 + 1);
    ac0 = MFMA(cpb[0], Bx0, ac0); ac0 = MFMA(cpb[1], Bx1, ac0);
    ac1 = MFMA(cpb[2], Bx0, ac1); ac1 = MFMA(cpb[3], Bx1, ac1);

    pack2(mB,           wv, lane, ah0, ah1);
    pack2(mB + 8 * 512, wv, lane, ac0, ac1);
    barrier_lds();  // B1

    f32x4 am0 = BIAS(2, mt0), am1 = BIAS(2, mt0 + 1);
    f32x4 ar0 = BIAS(4, mt0), ar1 = BIAS(4, mt0 + 1);
    #pragma unroll
    for (int i = 0; i < 16; ++i) {
      bf16x8 Bm = *(const bf16x8*)(mB + i * 512 + lane * 8);
      am0 = MFMA(as_bf(wm0f[i]), Bm, am0);
      am1 = MFMA(wm1[i], Bm, am1);
      int k = i & 7;
      bf16x8 a;
      if (k < 7) a = *(const bf16x8*)(r1Lp + ((i >> 3) * 7 + k) * 512);
      else       a = (i < 8) ? r1k7a : r1k7b;
      if (i < 8) ar0 = MFMA(a, Bh[k], ar0);
      else       ar1 = MFMA(a, Bh[k], ar1);
    }
    bf16x8 pob[8];
    #pragma unroll
    for (int p = 0; p < 8; ++p) pob[p] = *(const bf16x8*)(po_p + p * 512);
    {
      int tn = (t + 1 < TT) ? t + 1 : TT - 1;
      const float* xp = xbase + (size_t)tn * NB * 64;
      xr0 = *(const f32x4*)(xp);      xr1 = *(const f32x4*)(xp + 4);
      xr2 = *(const f32x4*)(xp + 32); xr3 = *(const f32x4*)(xp + 36);
    }
    pack2(uB, wv, lane, am0, am1);
    barrier_lds();  // B2

    bf16x8 Bu[8];
    #pragma unroll
    for (int kt = 0; kt < 8; ++kt)
      Bu[kt] = *(const bf16x8*)(uB + kt * 512 + lane * 8);
    {
      float p = 0.f;
      #pragma unroll
      for (int r = 0; r < 4; ++r)
        p += fmaxf(ar0[r], 0.f) * w2a[r] + fmaxf(ar1[r], 0.f) * w2b[r];
      p += __shfl_xor(p, 16, 64);
      p += __shfl_xor(p, 32, 64);
      if (lane < 16) outp[wv * 16 + lane] = p;
    }
    f32x4 ap0 = BIAS(3, mt0), ap1 = BIAS(3, mt0 + 1);
    #pragma unroll
    for (int i = 0; i < 16; ++i) {
      bf16x8 a = pob[i & 7];
      if (i < 8) ap0 = MFMA(a, Bu[i & 7], ap0);
      else       ap1 = MFMA(a, Bu[i & 7], ap1);
      if (i + 8 < 16) pob[i & 7] = *(const bf16x8*)(po_p + (i + 8) * 512);
    }
    pack2(hB, wv, lane, ap0, ap1);
    #pragma unroll
    for (int p = 0; p < 8; ++p) hpb[p] = *(const bf16x8*)(hp_p + p * 512);
    barrier_lds();  // B3
  }

  if (tid < 16) {
    float s = br2v;
    #pragma unroll
    for (int w = 0; w < 8; ++w) s += outp[w * 16 + tid];
    out[(size_t)(TT - 2) * NB + n0 + tid] = s;
  }
  barrier_lds();

  {
    bf16x8 Bh[8];
    #pragma unroll
    for (int kt = 0; kt < 8; ++kt)
      Bh[kt] = *(const bf16x8*)(hB + kt * 512 + lane * 8);
    f32x4 ar0 = BIAS(4, mt0), ar1 = BIAS(4, mt0 + 1);
    bf16x8 r1b[8];
    #pragma unroll
    for (int p = 0; p < 8; ++p) r1b[p] = *(const bf16x8*)(r1_p + p * 512);
    #pragma unroll
    for (int i = 0; i < 16; ++i) {
      bf16x8 a = r1b[i & 7];
      if (i < 8) ar0 = MFMA(a, Bh[i & 7], ar0);
      else       ar1 = MFMA(a, Bh[i & 7], ar1);
      if (i + 8 < 16) r1b[i & 7] = *(const bf16x8*)(r1_p + (i + 8) * 512);
    }
    float p = 0.f;
    #pragma unroll
    for (int r = 0; r < 4; ++r)
      p += fmaxf(ar0[r], 0.f) * w2a[r] + fmaxf(ar1[r], 0.f) * w2b[r];
    p += __shfl_xor(p, 16, 64);
    p += __shfl_xor(p, 32, 64);
    if (lane < 16) outp[wv * 16 + lane] = p;
    barrier_lds();
    if (tid < 16) {
      float s = br2v;
      #pragma unroll
      for (int w = 0; w < 8; ++w) s += outp[w * 16 + tid];
      out[(size_t)(TT - 1) * NB + n0 + tid] = s;
    }
  }
  #undef BIAS
}

extern "C" void kernel_launch(void* const* d_in, const int* in_sizes, int n_in,
                              void* d_out, int out_size, void* d_ws, size_t ws_size,
                              hipStream_t stream) {
  const float* x      = (const float*)d_in[0];
  const float* Whp    = (const float*)d_in[1];
  const float* bhp    = (const float*)d_in[2];
  const float* Wcp    = (const float*)d_in[3];
  const float* bcp    = (const float*)d_in[4];
  const float* Wm     = (const float*)d_in[5];
  const float* bm     = (const float*)d_in[6];
  const float* Whpost = (const float*)d_in[7];
  const float* bhpost = (const float*)d_in[8];
  const float* Wr1    = (const float*)d_in[9];
  const float* br1    = (const float*)d_in[10];
  const float* Wr2    = (const float*)d_in[11];
  const float* br2    = (const float*)d_in[12];
  __bf16* wsp = (__bf16*)d_ws;
  float*  out = (float*)d_out;

  if (ws_size < (size_t)TOT * sizeof(__bf16)) return;

  pack_weights<<<(TOT + 255) / 256, 256, 0, stream>>>(Whp, Wm, Wcp, Whpost, Wr1, wsp);

  const size_t H_BYTES = H_ELEMS * sizeof(__bf16);   // 268 MB
  if (ws_size >= (size_t)H_OFF_BYTES + H_BYTES) {
    __bf16* hist = (__bf16*)((char*)d_ws + H_OFF_BYTES);
    rnn_seq_c<<<64, 256, 0, stream>>>(x, wsp, hist, bhp, bcp, bm, bhpost);
    head_out<<<dim3(TT, 4), 512, 0, stream>>>(wsp, hist, br1, Wr2, br2, out);
  } else {
    rnn_seq<<<64, 512, 0, stream>>>(x, wsp, bhp, bcp, bm, bhpost, br1, Wr2,
                                    br2, out);
  }
}

// Round 6
// 2984.375 us; speedup vs baseline: 1.6634x; 1.6634x over previous
//
#include <hip/hip_runtime.h>
#include <hip/hip_bf16.h>

#define TT 512
#define NB 1024

typedef float f32x4 __attribute__((ext_vector_type(4)));
typedef __bf16 bf16x8 __attribute__((ext_vector_type(8)));

// ---- workspace layout (bf16 elems). All matrices stored as A-fragments for
// the TRANSPOSED GEMM  C^T[feature][batch] = W^T @ act^T :
//   frag(mt, kt, lane, j) at ((mt*KT + kt)*512 + lane*8 + j)
//   value = W[kappa][16*mt + (lane&15)]
#define OFF_HP 0
#define OFF_CP 65536
#define OFF_M  81920
#define OFF_PO 212992
#define OFF_R1 278528
#define TOT    344064

// h-history: hist[((t*64+blk)*8+fr)*512 + lane*8 + j], bf16.
#define H_OFF_BYTES (1u << 20)
#define H_ELEMS ((size_t)TT * 64 * 8 * 512)

// Force true register residency: the value's def becomes this asm, so the
// compiler cannot rematerialize it from memory inside the loop.
#define KEEP(v) asm volatile("" : "+v"(v))

__device__ __forceinline__ bf16x8 as_bf(const f32x4 v) {
  union U { f32x4 f; bf16x8 b; } u; u.f = v; return u.b;
}

__global__ __launch_bounds__(256) void pack_weights(
    const float* __restrict__ Whp, const float* __restrict__ Wm,
    const float* __restrict__ Wcp, const float* __restrict__ Whpost,
    const float* __restrict__ Wr1, __bf16* __restrict__ wsp) {
  int id = blockIdx.x * 256 + threadIdx.x;
  if (id >= TOT) return;
  int j = id & 7, lane = (id >> 3) & 63;
  int lq = lane >> 4, l15 = lane & 15;
  int rel, KT; const float* W; bool perm = true;
  if (id < OFF_CP)      { rel = id;          KT = 8;  W = Whp; }
  else if (id < OFF_M)  { rel = id - OFF_CP; KT = 2;  W = Wcp; perm = false; }
  else if (id < OFF_PO) { rel = id - OFF_M;  KT = 16; W = Wm; }
  else if (id < OFF_R1) { rel = id - OFF_PO; KT = 8;  W = Whpost; }
  else                  { rel = id - OFF_R1; KT = 8;  W = Wr1; }
  int ktm = rel >> 9;
  int kt = ktm % KT, mt = ktm / KT;
  int phi = 16 * mt + l15;
  int kk;
  if (perm) {
    int kb = (kt >= 8) ? kt - 8 : kt;          // only mesh has kt>=8
    kk = 32 * kb + 16 * (j >> 2) + 4 * lq + (j & 3);
    if (kt >= 8) kk += 256;                    // cp half of the concat
  } else {
    kk = 32 * kt + 8 * lq + j;
  }
  wsp[id] = (__bf16)W[kk * 256 + phi];
}

__device__ __forceinline__ float tanh_fast(float x) {
  float t = __expf(2.0f * x);
  return 1.0f - __fdividef(2.0f, t + 1.0f);
}

#define MFMA(a, b, c) __builtin_amdgcn_mfma_f32_16x16x32_bf16((a), (b), (c), 0, 0, 0)

// tanh + pack two mt-accumulators into ONE B-fragment (index fr).
__device__ __forceinline__ bf16x8 pack2(__bf16* region, int fr, int lane,
                                        const f32x4& a0, const f32x4& a1) {
  bf16x8 f;
  #pragma unroll
  for (int r = 0; r < 4; ++r) {
    f[r]     = (__bf16)tanh_fast(a0[r]);
    f[4 + r] = (__bf16)tanh_fast(a1[r]);
  }
  *(bf16x8*)(region + fr * 512 + lane * 8) = f;
  return f;
}

// Raw barrier: make LDS writes visible (lgkmcnt only) WITHOUT draining vmcnt.
__device__ __forceinline__ void barrier_lds() {
  asm volatile("s_waitcnt lgkmcnt(0)" ::: "memory");
  __builtin_amdgcn_s_barrier();
  asm volatile("" ::: "memory");
}

// ---------------------------------------------------------------------------
// rnn_seq_a (R4 structure, proven 2570us): 8 waves x 2 m-tiles,
// waves_per_eu(2,2). hp + mesh-hp pinned (128 V); mesh-cp kt8..14 in LDS;
// out-head deferred via hist. R6 change: po full-16 window pre-issued
// (8 at stage-2 top, 8 after mesh MFMAs) -> zero in-loop refills, every po
// load has >=300cy lead over its consuming MFMA. Same MFMA order as R4.
// ---------------------------------------------------------------------------
__global__ __launch_bounds__(512)
__attribute__((amdgpu_waves_per_eu(2, 2)))
void rnn_seq_a(
    const float* __restrict__ x, const __bf16* __restrict__ wsp,
    __bf16* __restrict__ hist,
    const float* __restrict__ bhp, const float* __restrict__ bcp,
    const float* __restrict__ bm, const float* __restrict__ bhpost) {
  __shared__ __align__(16) __bf16 hB[8 * 512];       // h state as B-frags (8K)
  __shared__ __align__(16) __bf16 mB[16 * 512];      // [hpB | cpB] (16K)
  __shared__ __align__(16) __bf16 uB[8 * 512];       // mesh output (8K)
  __shared__ __align__(16) __bf16 wmcL[112 * 512];   // mesh cp-half kt 8..14 (112K)
  __shared__ float lb[4 * 256];                      // bhp,bcp,bm,bhpost (4K)

  const int tid  = threadIdx.x;
  const int wv   = tid >> 6;
  const int lane = tid & 63;
  const int lq   = lane >> 4, l15 = lane & 15;
  const int n0   = blockIdx.x * 16;
  const int mt0  = 2 * wv;

  if (tid < 256) {
    lb[0 * 256 + tid] = bhp[tid];
    lb[1 * 256 + tid] = bcp[tid];
    lb[2 * 256 + tid] = bm[tid];
    lb[3 * 256 + tid] = bhpost[tid];
  }
  for (int i = tid; i < 8 * 512; i += 512) hB[i] = (__bf16)0.0f;

  // one-time: cache mesh cp-half frags (kt 8..14 of every mt) in LDS.
  for (int v = tid; v < 112 * 64; v += 512) {
    int frag = v >> 6, lp = v & 63;
    int mt = frag / 7, c = frag - mt * 7;
    ((bf16x8*)wmcL)[v] =
        *(const bf16x8*)(wsp + OFF_M + (size_t)(mt * 16 + 8 + c) * 512 + lp * 8);
  }

  #define BIAS(a, m) (*(const f32x4*)(lb + (a) * 256 + (m) * 16 + 4 * lq))

  // ---- FORCED register-resident weights: hp (16 frags) + mesh-hp (16) ----
  f32x4 hpw[16], wmh[16];
  {
    const __bf16* hp0 = wsp + OFF_HP + (size_t)(mt0 * 8) * 512 + lane * 8;
    const __bf16* mp  = wsp + OFF_M + (size_t)(mt0 * 16) * 512 + lane * 8;
    #pragma unroll
    for (int i = 0; i < 16; ++i) hpw[i] = *(const f32x4*)(hp0 + i * 512);
    #pragma unroll
    for (int kt = 0; kt < 8; ++kt) {
      wmh[kt]     = *(const f32x4*)(mp + kt * 512);          // (mt0,   kt)
      wmh[8 + kt] = *(const f32x4*)(mp + (16 + kt) * 512);   // (mt0+1, kt)
    }
  }
  #pragma unroll
  for (int i = 0; i < 16; ++i) { KEEP(hpw[i]); KEEP(wmh[i]); }

  const __bf16* cp_p   = wsp + OFF_CP + (size_t)(mt0 * 2) * 512 + lane * 8;
  const __bf16* po_p   = wsp + OFF_PO + (size_t)(mt0 * 8) * 512 + lane * 8;
  const __bf16* wmk15a = wsp + OFF_M + (size_t)(mt0 * 16 + 15) * 512 + lane * 8;
  const __bf16* wmk15b = wsp + OFF_M + (size_t)((mt0 + 1) * 16 + 15) * 512 + lane * 8;
  const __bf16* wc0 = wmcL + (size_t)(mt0 * 7) * 512 + lane * 8;
  const __bf16* wc1 = wmcL + (size_t)((mt0 + 1) * 7) * 512 + lane * 8;
  __bf16* hst = hist + (size_t)(blockIdx.x * 8 + wv) * 512 + lane * 8;

  __syncthreads();

  const float* xbase = x + (size_t)(n0 + l15) * 64 + 8 * lq;
  f32x4 xr0 = *(const f32x4*)(xbase);
  f32x4 xr1 = *(const f32x4*)(xbase + 4);
  f32x4 xr2 = *(const f32x4*)(xbase + 32);
  f32x4 xr3 = *(const f32x4*)(xbase + 36);

  for (int t = 0; t < TT; ++t) {
    bf16x8 Bx0, Bx1;
    #pragma unroll
    for (int j = 0; j < 4; ++j) {
      Bx0[j] = (__bf16)xr0[j]; Bx0[4 + j] = (__bf16)xr1[j];
      Bx1[j] = (__bf16)xr2[j]; Bx1[4 + j] = (__bf16)xr3[j];
    }

    // ---- stage 1: hp = h@Whp + bhp (weights in regs!) ; cp = x@Wcp + bcp --
    bf16x8 cpb[4];
    #pragma unroll
    for (int p = 0; p < 4; ++p) cpb[p] = *(const bf16x8*)(cp_p + p * 512);
    bf16x8 wk15a = *(const bf16x8*)(wmk15a);
    bf16x8 wk15b = *(const bf16x8*)(wmk15b);
    bf16x8 Bh[8];
    #pragma unroll
    for (int kt = 0; kt < 8; ++kt)
      Bh[kt] = *(const bf16x8*)(hB + kt * 512 + lane * 8);

    f32x4 ah0 = BIAS(0, mt0), ah1 = BIAS(0, mt0 + 1);
    #pragma unroll
    for (int i = 0; i < 16; ++i) {
      bf16x8 a = as_bf(hpw[i]);
      if (i < 8) ah0 = MFMA(a, Bh[i & 7], ah0);
      else       ah1 = MFMA(a, Bh[i & 7], ah1);
    }
    f32x4 ac0 = BIAS(1, mt0), ac1 = BIAS(1, mt0 + 1);
    ac0 = MFMA(cpb[0], Bx0, ac0); ac0 = MFMA(cpb[1], Bx1, ac0);
    ac1 = MFMA(cpb[2], Bx0, ac1); ac1 = MFMA(cpb[3], Bx1, ac1);

    pack2(mB,           wv, lane, ah0, ah1);
    pack2(mB + 8 * 512, wv, lane, ac0, ac1);
    barrier_lds();  // B1

    // ---- stage 2: u = cat@Wm + bm  (hp-half in regs, cp-half LDS + k15) ---
    // issue first half of the po window NOW: lead = whole mesh loop (~600cy).
    bf16x8 pob[16];
    #pragma unroll
    for (int p = 0; p < 8; ++p) pob[p] = *(const bf16x8*)(po_p + p * 512);

    f32x4 am0 = BIAS(2, mt0), am1 = BIAS(2, mt0 + 1);
    #pragma unroll
    for (int i = 0; i < 16; ++i) {
      bf16x8 Bm = *(const bf16x8*)(mB + i * 512 + lane * 8);
      bf16x8 w0, w1;
      if (i < 8)       { w0 = as_bf(wmh[i]); w1 = as_bf(wmh[8 + i]); }
      else if (i < 15) { w0 = *(const bf16x8*)(wc0 + (i - 8) * 512);
                         w1 = *(const bf16x8*)(wc1 + (i - 8) * 512); }
      else             { w0 = wk15a; w1 = wk15b; }
      am0 = MFMA(w0, Bm, am0);
      am1 = MFMA(w1, Bm, am1);
    }
    // second half of po window (lead = B2 + >=8 MFMA slots, ~300cy) + next x
    #pragma unroll
    for (int p = 8; p < 16; ++p) pob[p] = *(const bf16x8*)(po_p + p * 512);
    {
      int tn = (t + 1 < TT) ? t + 1 : TT - 1;
      const float* xp = xbase + (size_t)tn * NB * 64;
      xr0 = *(const f32x4*)(xp);      xr1 = *(const f32x4*)(xp + 4);
      xr2 = *(const f32x4*)(xp + 32); xr3 = *(const f32x4*)(xp + 36);
    }
    pack2(uB, wv, lane, am0, am1);
    barrier_lds();  // B2

    // ---- stage 3: h = tanh(u @ Whpost + bhpost) ; store h to history ------
    bf16x8 Bu[8];
    #pragma unroll
    for (int kt = 0; kt < 8; ++kt)
      Bu[kt] = *(const bf16x8*)(uB + kt * 512 + lane * 8);
    f32x4 ap0 = BIAS(3, mt0), ap1 = BIAS(3, mt0 + 1);
    #pragma unroll
    for (int i = 0; i < 16; ++i) {      // no refills: pob fully pre-issued
      bf16x8 a = pob[i];
      if (i < 8) ap0 = MFMA(a, Bu[i & 7], ap0);
      else       ap1 = MFMA(a, Bu[i & 7], ap1);
    }
    bf16x8 f = pack2(hB, wv, lane, ap0, ap1);
    *(bf16x8*)(hst + (size_t)t * (64 * 8 * 512)) = f;   // fire-and-forget
    barrier_lds();  // B3
  }
  #undef BIAS
}

// ---------------------------------------------------------------------------
// head: out[t] = relu(h(t)@Wr1 + br1)@Wr2 + br2, fully parallel.
// R6: raw barriers (no vmcnt drain) + double-buffered Bh prefetch (named
// A/B buffers, static indexing) + grid (TT,8). Same MFMA/reduce order.
// ---------------------------------------------------------------------------
__global__ __launch_bounds__(512) void head_out(
    const __bf16* __restrict__ wsp, const __bf16* __restrict__ hist,
    const float* __restrict__ br1, const float* __restrict__ Wr2,
    const float* __restrict__ br2, float* __restrict__ out) {
  __shared__ float outp[128];
  const int tid  = threadIdx.x;
  const int wv   = tid >> 6;
  const int lane = tid & 63;
  const int lq   = lane >> 4;
  const int t    = blockIdx.x;
  const int nb0  = blockIdx.y * 8;
  const int mt0  = 2 * wv;

  f32x4 r1w[16];
  {
    const __bf16* r1p = wsp + OFF_R1 + (size_t)(mt0 * 8) * 512 + lane * 8;
    #pragma unroll
    for (int i = 0; i < 16; ++i) r1w[i] = *(const f32x4*)(r1p + i * 512);
  }
  #pragma unroll
  for (int i = 0; i < 16; ++i) KEEP(r1w[i]);

  const f32x4 w2a = *(const f32x4*)(Wr2 + mt0 * 16 + 4 * lq);
  const f32x4 w2b = *(const f32x4*)(Wr2 + (mt0 + 1) * 16 + 4 * lq);
  const f32x4 b0  = *(const f32x4*)(br1 + mt0 * 16 + 4 * lq);
  const f32x4 b1  = *(const f32x4*)(br1 + (mt0 + 1) * 16 + 4 * lq);
  const float br2v = br2[0];

  const __bf16* hb = hist + (size_t)(t * 64) * 8 * 512 + lane * 8;

  #define LOADH(dst, nb)                                                    \
    { const __bf16* hp_ = hb + (size_t)(nb) * 8 * 512;                      \
      _Pragma("unroll")                                                     \
      for (int k_ = 0; k_ < 8; ++k_)                                        \
        dst[k_] = *(const bf16x8*)(hp_ + k_ * 512); }

  #define COMPUTE(src, nb)                                                  \
    { f32x4 ar0 = b0, ar1 = b1;                                             \
      _Pragma("unroll")                                                     \
      for (int i_ = 0; i_ < 16; ++i_) {                                     \
        if (i_ < 8) ar0 = MFMA(as_bf(r1w[i_]), src[i_], ar0);               \
        else        ar1 = MFMA(as_bf(r1w[i_]), src[i_ - 8], ar1);           \
      }                                                                     \
      float p_ = 0.f;                                                       \
      _Pragma("unroll")                                                     \
      for (int r_ = 0; r_ < 4; ++r_)                                        \
        p_ += fmaxf(ar0[r_], 0.f) * w2a[r_] + fmaxf(ar1[r_], 0.f) * w2b[r_];\
      p_ += __shfl_xor(p_, 16, 64);                                         \
      p_ += __shfl_xor(p_, 32, 64);                                         \
      if (lane < 16) outp[wv * 16 + lane] = p_;                             \
      barrier_lds();                                                        \
      if (tid < 16) {                                                       \
        float s_ = br2v;                                                    \
        _Pragma("unroll")                                                   \
        for (int w_ = 0; w_ < 8; ++w_) s_ += outp[w_ * 16 + tid];           \
        out[(size_t)t * NB + (nb) * 16 + tid] = s_;                         \
      }                                                                     \
      barrier_lds(); }

  bf16x8 BA[8], BB[8];
  LOADH(BA, nb0);
  #pragma unroll
  for (int k = 0; k < 8; k += 2) {
    LOADH(BB, nb0 + k + 1);          // flies across COMPUTE's raw barriers
    COMPUTE(BA, nb0 + k);
    LOADH(BA, (k + 2 < 8) ? nb0 + k + 2 : nb0);   // last: harmless reload
    COMPUTE(BB, nb0 + k + 1);
  }
  #undef LOADH
  #undef COMPUTE
}

// ---------------------------------------------------------------------------
// Fallback (small ws): R4 variant-B kernel, unchanged.
// ---------------------------------------------------------------------------
__global__ __launch_bounds__(512)
__attribute__((amdgpu_waves_per_eu(2, 2)))
void rnn_seq(
    const float* __restrict__ x, const __bf16* __restrict__ wsp,
    const float* __restrict__ bhp, const float* __restrict__ bcp,
    const float* __restrict__ bm, const float* __restrict__ bhpost,
    const float* __restrict__ br1, const float* __restrict__ Wr2,
    const float* __restrict__ br2, float* __restrict__ out) {
  __shared__ __align__(16) __bf16 hB[8 * 512];
  __shared__ __align__(16) __bf16 mB[16 * 512];
  __shared__ __align__(16) __bf16 uB[8 * 512];
  __shared__ __align__(16) __bf16 r1L[112 * 512];
  __shared__ float lb[5 * 256];
  __shared__ float outp[128];

  const int tid  = threadIdx.x;
  const int wv   = tid >> 6;
  const int lane = tid & 63;
  const int lq   = lane >> 4, l15 = lane & 15;
  const int n0   = blockIdx.x * 16;
  const int mt0  = 2 * wv;

  if (tid < 256) {
    lb[0 * 256 + tid] = bhp[tid];
    lb[1 * 256 + tid] = bcp[tid];
    lb[2 * 256 + tid] = bm[tid];
    lb[3 * 256 + tid] = bhpost[tid];
    lb[4 * 256 + tid] = br1[tid];
  }
  for (int i = tid; i < 8 * 512; i += 512) hB[i] = (__bf16)0.0f;

  for (int v = tid; v < 112 * 64; v += 512) {
    int frag = v >> 6, lp = v & 63;
    int mt = frag / 7, kt = frag - mt * 7;
    ((bf16x8*)r1L)[v] =
        *(const bf16x8*)(wsp + OFF_R1 + (size_t)(mt * 8 + kt) * 512 + lp * 8);
  }
  const float br2v = br2[0];

  #define BIAS(a, m) (*(const f32x4*)(lb + (a) * 256 + (m) * 16 + 4 * lq))
  const f32x4 w2a = *(const f32x4*)(Wr2 + mt0 * 16 + 4 * lq);
  const f32x4 w2b = *(const f32x4*)(Wr2 + (mt0 + 1) * 16 + 4 * lq);

  f32x4 wm0f[16]; bf16x8 wm1[16];
  {
    const __bf16* mp = wsp + OFF_M + (size_t)(mt0 * 16) * 512 + lane * 8;
    #pragma unroll
    for (int kt = 0; kt < 16; ++kt) {
      wm0f[kt] = *(const f32x4*)(mp + kt * 512);
      wm1[kt]  = *(const bf16x8*)(mp + (16 + kt) * 512);
    }
  }
  #pragma unroll
  for (int i = 0; i < 16; ++i) KEEP(wm0f[i]);

  const __bf16* hp_p = wsp + OFF_HP + (size_t)(mt0 * 8) * 512 + lane * 8;
  const __bf16* r1_p = wsp + OFF_R1 + (size_t)(mt0 * 8) * 512 + lane * 8;
  const __bf16* cp_p = wsp + OFF_CP + (size_t)(mt0 * 2) * 512 + lane * 8;
  const __bf16* po_p = wsp + OFF_PO + (size_t)(mt0 * 8) * 512 + lane * 8;
  const __bf16* r1Lp = r1L + (size_t)(mt0 * 7) * 512 + lane * 8;

  __syncthreads();

  const float* xbase = x + (size_t)(n0 + l15) * 64 + 8 * lq;
  f32x4 xr0 = *(const f32x4*)(xbase);
  f32x4 xr1 = *(const f32x4*)(xbase + 4);
  f32x4 xr2 = *(const f32x4*)(xbase + 32);
  f32x4 xr3 = *(const f32x4*)(xbase + 36);

  bf16x8 hpb[8];
  #pragma unroll
  for (int p = 0; p < 8; ++p) hpb[p] = *(const bf16x8*)(hp_p + p * 512);

  for (int t = 0; t < TT; ++t) {
    if (t >= 2 && tid < 16) {
      float s = br2v;
      #pragma unroll
      for (int w = 0; w < 8; ++w) s += outp[w * 16 + tid];
      out[(size_t)(t - 2) * NB + n0 + tid] = s;
    }

    bf16x8 Bx0, Bx1;
    #pragma unroll
    for (int j = 0; j < 4; ++j) {
      Bx0[j] = (__bf16)xr0[j]; Bx0[4 + j] = (__bf16)xr1[j];
      Bx1[j] = (__bf16)xr2[j]; Bx1[4 + j] = (__bf16)xr3[j];
    }

    bf16x8 cpb[4];
    #pragma unroll
    for (int p = 0; p < 4; ++p) cpb[p] = *(const bf16x8*)(cp_p + p * 512);
    bf16x8 r1k7a = *(const bf16x8*)(r1_p + 7 * 512);
    bf16x8 r1k7b = *(const bf16x8*)(r1_p + 15 * 512);
    bf16x8 Bh[8];
    #pragma unroll
    for (int kt = 0; kt < 8; ++kt)
      Bh[kt] = *(const bf16x8*)(hB + kt * 512 + lane * 8);

    f32x4 ah0 = BIAS(0, mt0), ah1 = BIAS(0, mt0 + 1);
    #pragma unroll
    for (int i = 0; i < 16; ++i) {
      bf16x8 a = hpb[i & 7];
      if (i < 8) ah0 = MFMA(a, Bh[i & 7], ah0);
      else       ah1 = MFMA(a, Bh[i & 7], ah1);
      if (i + 8 < 16) hpb[i & 7] = *(const bf16x8*)(hp_p + (i + 8) * 512);
    }
    f32x4 ac0 = BIAS(1, mt0), ac1 = BIAS(1, mt0 + 1);
    ac0 = MFMA(cpb[0], Bx0, ac0); ac0 = MFMA(cpb[1], Bx1, ac0);
    ac1 = MFMA(cpb[2], Bx0, ac1); ac1 = MFMA(cpb[3], Bx1, ac1);

    pack2(mB,           wv, lane, ah0, ah1);
    pack2(mB + 8 * 512, wv, lane, ac0, ac1);
    barrier_lds();  // B1

    f32x4 am0 = BIAS(2, mt0), am1 = BIAS(2, mt0 + 1);
    f32x4 ar0 = BIAS(4, mt0), ar1 = BIAS(4, mt0 + 1);
    #pragma unroll
    for (int i = 0; i < 16; ++i) {
      bf16x8 Bm = *(const bf16x8*)(mB + i * 512 + lane * 8);
      am0 = MFMA(as_bf(wm0f[i]), Bm, am0);
      am1 = MFMA(wm1[i], Bm, am1);
      int k = i & 7;
      bf16x8 a;
      if (k < 7) a = *(const bf16x8*)(r1Lp + ((i >> 3) * 7 + k) * 512);
      else       a = (i < 8) ? r1k7a : r1k7b;
      if (i < 8) ar0 = MFMA(a, Bh[k], ar0);
      else       ar1 = MFMA(a, Bh[k], ar1);
    }
    bf16x8 pob[8];
    #pragma unroll
    for (int p = 0; p < 8; ++p) pob[p] = *(const bf16x8*)(po_p + p * 512);
    {
      int tn = (t + 1 < TT) ? t + 1 : TT - 1;
      const float* xp = xbase + (size_t)tn * NB * 64;
      xr0 = *(const f32x4*)(xp);      xr1 = *(const f32x4*)(xp + 4);
      xr2 = *(const f32x4*)(xp + 32); xr3 = *(const f32x4*)(xp + 36);
    }
    pack2(uB, wv, lane, am0, am1);
    barrier_lds();  // B2

    bf16x8 Bu[8];
    #pragma unroll
    for (int kt = 0; kt < 8; ++kt)
      Bu[kt] = *(const bf16x8*)(uB + kt * 512 + lane * 8);
    {
      float p = 0.f;
      #pragma unroll
      for (int r = 0; r < 4; ++r)
        p += fmaxf(ar0[r], 0.f) * w2a[r] + fmaxf(ar1[r], 0.f) * w2b[r];
      p += __shfl_xor(p, 16, 64);
      p += __shfl_xor(p, 32, 64);
      if (lane < 16) outp[wv * 16 + lane] = p;
    }
    f32x4 ap0 = BIAS(3, mt0), ap1 = BIAS(3, mt0 + 1);
    #pragma unroll
    for (int i = 0; i < 16; ++i) {
      bf16x8 a = pob[i & 7];
      if (i < 8) ap0 = MFMA(a, Bu[i & 7], ap0);
      else       ap1 = MFMA(a, Bu[i & 7], ap1);
      if (i + 8 < 16) pob[i & 7] = *(const bf16x8*)(po_p + (i + 8) * 512);
    }
    pack2(hB, wv, lane, ap0, ap1);
    #pragma unroll
    for (int p = 0; p < 8; ++p) hpb[p] = *(const bf16x8*)(hp_p + p * 512);
    barrier_lds();  // B3
  }

  if (tid < 16) {
    float s = br2v;
    #pragma unroll
    for (int w = 0; w < 8; ++w) s += outp[w * 16 + tid];
    out[(size_t)(TT - 2) * NB + n0 + tid] = s;
  }
  barrier_lds();

  {
    bf16x8 Bh[8];
    #pragma unroll
    for (int kt = 0; kt < 8; ++kt)
      Bh[kt] = *(const bf16x8*)(hB + kt * 512 + lane * 8);
    f32x4 ar0 = BIAS(4, mt0), ar1 = BIAS(4, mt0 + 1);
    bf16x8 r1b[8];
    #pragma unroll
    for (int p = 0; p < 8; ++p) r1b[p] = *(const bf16x8*)(r1_p + p * 512);
    #pragma unroll
    for (int i = 0; i < 16; ++i) {
      bf16x8 a = r1b[i & 7];
      if (i < 8) ar0 = MFMA(a, Bh[i & 7], ar0);
      else       ar1 = MFMA(a, Bh[i & 7], ar1);
      if (i + 8 < 16) r1b[i & 7] = *(const bf16x8*)(r1_p + (i + 8) * 512);
    }
    float p = 0.f;
    #pragma unroll
    for (int r = 0; r < 4; ++r)
      p += fmaxf(ar0[r], 0.f) * w2a[r] + fmaxf(ar1[r], 0.f) * w2b[r];
    p += __shfl_xor(p, 16, 64);
    p += __shfl_xor(p, 32, 64);
    if (lane < 16) outp[wv * 16 + lane] = p;
    barrier_lds();
    if (tid < 16) {
      float s = br2v;
      #pragma unroll
      for (int w = 0; w < 8; ++w) s += outp[w * 16 + tid];
      out[(size_t)(TT - 1) * NB + n0 + tid] = s;
    }
  }
  #undef BIAS
}

extern "C" void kernel_launch(void* const* d_in, const int* in_sizes, int n_in,
                              void* d_out, int out_size, void* d_ws, size_t ws_size,
                              hipStream_t stream) {
  const float* x      = (const float*)d_in[0];
  const float* Whp    = (const float*)d_in[1];
  const float* bhp    = (const float*)d_in[2];
  const float* Wcp    = (const float*)d_in[3];
  const float* bcp    = (const float*)d_in[4];
  const float* Wm     = (const float*)d_in[5];
  const float* bm     = (const float*)d_in[6];
  const float* Whpost = (const float*)d_in[7];
  const float* bhpost = (const float*)d_in[8];
  const float* Wr1    = (const float*)d_in[9];
  const float* br1    = (const float*)d_in[10];
  const float* Wr2    = (const float*)d_in[11];
  const float* br2    = (const float*)d_in[12];
  __bf16* wsp = (__bf16*)d_ws;
  float*  out = (float*)d_out;

  if (ws_size < (size_t)TOT * sizeof(__bf16)) return;

  pack_weights<<<(TOT + 255) / 256, 256, 0, stream>>>(Whp, Wm, Wcp, Whpost, Wr1, wsp);

  const size_t H_BYTES = H_ELEMS * sizeof(__bf16);   // 268 MB
  if (ws_size >= (size_t)H_OFF_BYTES + H_BYTES) {
    __bf16* hist = (__bf16*)((char*)d_ws + H_OFF_BYTES);
    rnn_seq_a<<<64, 512, 0, stream>>>(x, wsp, hist, bhp, bcp, bm, bhpost);
    head_out<<<dim3(TT, 8), 512, 0, stream>>>(wsp, hist, br1, Wr2, br2, out);
  } else {
    rnn_seq<<<64, 512, 0, stream>>>(x, wsp, bhp, bcp, bm, bhpost, br1, Wr2,
                                    br2, out);
  }
}